// Round 1
// baseline (290.956 us; speedup 1.0000x reference)
//
#include <hip/hip_runtime.h>

#define N_ANCHORS 4000000
#define NPAIR4    2000000      // float4 count in score (N*2/4)
#define M_TOP     2000
#define NBINS     1024
#define CAP       8192
#define NMS_THR_F 0.7f
#define SCORE_THR_F 0.5f

// workspace layout (bytes)
#define OFF_HIST   0            // 1024 u32  = 4096
#define OFF_META   4096         // 16 u32    = 64   (meta[0]=counter, meta[1]=T)
#define OFF_KEYS   4352         // 8192 u64  = 65536
#define OFF_SORTED 69888        // 2000 u64  = 16000
#define OFF_BOXES  85888        // 2000 f4   = 32000
#define OFF_FLAGS  117888       // 2000 u32  = 8000
#define OFF_KEEPW  125888       // 32 u64    = 256
#define OFF_MASK   131072       // 2000*32 u64 = 512000  (end 643072)
#define ZERO_BYTES 69888        // hist + meta + keys

// ---------------- pass 1: histogram of score[:,1] bits ----------------
__global__ void hist_kernel(const float4* __restrict__ s4, unsigned int* __restrict__ hist) {
  __shared__ unsigned int h[NBINS];
  for (int i = threadIdx.x; i < NBINS; i += blockDim.x) h[i] = 0;
  __syncthreads();
  int nt = gridDim.x * blockDim.x;
  for (int i = blockIdx.x * blockDim.x + threadIdx.x; i < NPAIR4; i += nt) {
    float4 v = s4[i];
    if (v.y > SCORE_THR_F) {
      unsigned b = (__float_as_uint(v.y) - 0x3F000000u) >> 13;
      atomicAdd(&h[b > 1023u ? 1023u : b], 1u);
    }
    if (v.w > SCORE_THR_F) {
      unsigned b = (__float_as_uint(v.w) - 0x3F000000u) >> 13;
      atomicAdd(&h[b > 1023u ? 1023u : b], 1u);
    }
  }
  __syncthreads();
  for (int i = threadIdx.x; i < NBINS; i += blockDim.x)
    if (h[i]) atomicAdd(&hist[i], h[i]);
}

// ---------------- find bit-threshold T so that count(bits>=T) >= M ----------------
__global__ void thresh_kernel(const unsigned int* __restrict__ hist, unsigned int* __restrict__ meta) {
  if (threadIdx.x == 0) {
    unsigned s = 0; int bstar = 0;
    for (int b = NBINS - 1; b >= 0; --b) {
      s += hist[b];
      if (s >= M_TOP) { bstar = b; break; }
    }
    meta[1] = 0x3F000000u + ((unsigned)bstar << 13);
  }
}

// ---------------- pass 2: compact candidate keys ----------------
__global__ void compact_kernel(const float4* __restrict__ s4, unsigned int* __restrict__ meta,
                               unsigned long long* __restrict__ keys) {
  unsigned T = meta[1];
  int nt = gridDim.x * blockDim.x;
  for (int i = blockIdx.x * blockDim.x + threadIdx.x; i < NPAIR4; i += nt) {
    float4 v = s4[i];
    unsigned by = __float_as_uint(v.y), bw = __float_as_uint(v.w);
    if (v.y > SCORE_THR_F && by >= T) {
      unsigned pos = atomicAdd(&meta[0], 1u);
      if (pos < CAP)
        keys[pos] = ((unsigned long long)by << 32) |
                    (unsigned long long)(0xFFFFFFFFu - (unsigned)(2 * i));
    }
    if (v.w > SCORE_THR_F && bw >= T) {
      unsigned pos = atomicAdd(&meta[0], 1u);
      if (pos < CAP)
        keys[pos] = ((unsigned long long)bw << 32) |
                    (unsigned long long)(0xFFFFFFFFu - (unsigned)(2 * i + 1));
    }
  }
}

// ---------------- single-block bitonic sort (top-2000 of <=8192) ----------------
// sort ascending on ~key  ==  descending on key (value desc, index asc on ties)
__global__ __launch_bounds__(1024) void sort_kernel(const unsigned long long* __restrict__ keys,
                                                    unsigned long long* __restrict__ sorted) {
  __shared__ unsigned long long A[CAP];   // 64 KB
  int tid = threadIdx.x;
  for (int i = tid; i < CAP; i += 1024) A[i] = ~keys[i];
  for (unsigned k = 2; k <= CAP; k <<= 1) {
    for (unsigned j = k >> 1; j; j >>= 1) {
      __syncthreads();
      for (unsigned t = tid; t < CAP / 2; t += 1024) {
        unsigned i = ((t & ~(j - 1)) << 1) | (t & (j - 1));
        unsigned p = i | j;
        bool up = ((i & k) == 0);
        unsigned long long a = A[i], b = A[p];
        if ((a > b) == up) { A[i] = b; A[p] = a; }
      }
    }
  }
  __syncthreads();
  for (int i = tid; i < M_TOP; i += 1024) sorted[i] = ~A[i];
}

// ---------------- decode + clip + keep0 flags (strict IEEE fp32, numpy op order) ----------------
__global__ void decode_kernel(const unsigned long long* __restrict__ sorted,
                              const float4* __restrict__ anchors,
                              const float4* __restrict__ deltas,
                              float4* __restrict__ boxes,
                              unsigned int* __restrict__ flags) {
  int i = blockIdx.x * blockDim.x + threadIdx.x;
  if (i >= M_TOP) return;
  unsigned long long key = sorted[i];
  float4 outb = make_float4(0.f, 0.f, 0.f, 0.f);
  unsigned keep0 = 0;
  if (key != 0ull) {   // real candidate (valid == true)
    unsigned idx = 0xFFFFFFFFu - (unsigned)(key & 0xFFFFFFFFull);
    float4 a = anchors[idx];
    float4 d = deltas[idx];
    float w  = __fsub_rn(a.z, a.x);
    float h  = __fsub_rn(a.w, a.y);
    float cx = __fadd_rn(a.x, __fmul_rn(0.5f, w));
    float cy = __fadd_rn(a.y, __fmul_rn(0.5f, h));
    float ncx = __fadd_rn(cx, __fmul_rn(d.x, w));
    float ncy = __fadd_rn(cy, __fmul_rn(d.y, h));
    float e2 = (float)exp((double)d.z);   // ~correctly-rounded fp32 exp
    float e3 = (float)exp((double)d.w);
    float nw = __fmul_rn(w, e2);
    float nh = __fmul_rn(h, e3);
    float hx = __fmul_rn(0.5f, nw);
    float hy = __fmul_rn(0.5f, nh);
    float x1 = __fsub_rn(ncx, hx), y1 = __fsub_rn(ncy, hy);
    float x2 = __fadd_rn(ncx, hx), y2 = __fadd_rn(ncy, hy);
    x1 = fminf(fmaxf(x1, 0.f), 1024.f);
    y1 = fminf(fmaxf(y1, 0.f), 1024.f);
    x2 = fminf(fmaxf(x2, 0.f), 1024.f);
    y2 = fminf(fmaxf(y2, 0.f), 1024.f);
    bool big = (__fsub_rn(x2, x1) >= 1.0f) && (__fsub_rn(y2, y1) >= 1.0f);
    keep0 = big ? 1u : 0u;
    outb = make_float4(x1, y1, x2, y2);
  }
  boxes[i] = outb;
  flags[i] = keep0;
}

// ---------------- suppression bitmask: mask[i][w] bit l = (iou(i, w*64+l) > thr) & (col > i) ----------------
__global__ __launch_bounds__(64) void mask_kernel(const float4* __restrict__ boxes,
                                                  unsigned long long* __restrict__ mask) {
  int row  = blockIdx.x >> 5;
  int word = blockIdx.x & 31;
  int lane = threadIdx.x;
  int col  = word * 64 + lane;
  float4 bi = boxes[row];
  float4 bj = boxes[col < M_TOP ? col : 0];
  float ai = __fmul_rn(__fsub_rn(bi.z, bi.x), __fsub_rn(bi.w, bi.y));
  float aj = __fmul_rn(__fsub_rn(bj.z, bj.x), __fsub_rn(bj.w, bj.y));
  float ltx = fmaxf(bi.x, bj.x), lty = fmaxf(bi.y, bj.y);
  float rbx = fminf(bi.z, bj.z), rby = fminf(bi.w, bj.w);
  float wx = fmaxf(__fsub_rn(rbx, ltx), 0.f);
  float wy = fmaxf(__fsub_rn(rby, lty), 0.f);
  float inter = __fmul_rn(wx, wy);
  float den = __fadd_rn(__fsub_rn(__fadd_rn(ai, aj), inter), 1e-9f);
  float iou = __fdiv_rn(inter, den);
  bool pred = (col > row) && (col < M_TOP) && (iou > NMS_THR_F);
  unsigned long long bal = __ballot(pred);
  if (lane == 0) mask[(size_t)row * 32 + word] = bal;
}

// ---------------- serial greedy NMS reduce (1 wave) ----------------
__global__ __launch_bounds__(64) void reduce_kernel(const unsigned long long* __restrict__ mask,
                                                    const unsigned int* __restrict__ flags,
                                                    unsigned long long* __restrict__ keepw) {
  int lane = threadIdx.x;
  unsigned long long k0 = 0, rem = 0;
  // pack keep0 flags into 32 words (lane w holds word w)
  for (int w = 0; w < 32; ++w) {
    int i = w * 64 + lane;
    unsigned f = (i < M_TOP) ? flags[i] : 0u;
    unsigned long long bal = __ballot(f != 0u);
    if (lane == w) k0 = bal;
  }
  int myw = lane & 31;
  for (int c = 0; c < 32; ++c) {
    unsigned long long cur = __shfl(k0 & ~rem, c);   // alive word for this chunk
    int nb = (c == 31) ? (M_TOP - 31 * 64) : 64;
    const unsigned long long* rowbase = mask + (size_t)(c * 64) * 32;
    #pragma unroll 16
    for (int b = 0; b < nb; ++b) {
      unsigned long long mw = rowbase[(size_t)b * 32 + myw];  // row's word for my lane
      unsigned long long mc = rowbase[(size_t)b * 32 + c];    // row's diagonal word (broadcast)
      unsigned long long am = ((cur >> b) & 1ull) ? ~0ull : 0ull;
      cur &= ~(mc & am);     // suppress later bits in this chunk
      rem |= (mw & am);      // accumulate suppression for future chunks
    }
  }
  if (lane < 32) keepw[lane] = k0 & ~rem;
}

// ---------------- write outputs: boxes_out (2000x4) then keep (2000) ----------------
__global__ void final_kernel(const float4* __restrict__ boxes,
                             const unsigned long long* __restrict__ keepw,
                             float* __restrict__ out) {
  int i = blockIdx.x * blockDim.x + threadIdx.x;
  if (i >= M_TOP) return;
  unsigned long long wbits = keepw[i >> 6];
  int kb = (int)((wbits >> (i & 63)) & 1ull);
  float4 b = boxes[i];
  float4 o = kb ? b : make_float4(0.f, 0.f, 0.f, 0.f);
  ((float4*)out)[i] = o;
  out[4 * M_TOP + i] = kb ? 1.0f : 0.0f;
}

extern "C" void kernel_launch(void* const* d_in, const int* in_sizes, int n_in,
                              void* d_out, int out_size, void* d_ws, size_t ws_size,
                              hipStream_t stream) {
  const float* anchors = (const float*)d_in[0];
  const float* score   = (const float*)d_in[1];
  const float* boxreg  = (const float*)d_in[2];
  float* out = (float*)d_out;
  char* ws = (char*)d_ws;

  unsigned int*       hist   = (unsigned int*)(ws + OFF_HIST);
  unsigned int*       meta   = (unsigned int*)(ws + OFF_META);
  unsigned long long* keys   = (unsigned long long*)(ws + OFF_KEYS);
  unsigned long long* sorted = (unsigned long long*)(ws + OFF_SORTED);
  float4*             boxes  = (float4*)(ws + OFF_BOXES);
  unsigned int*       flags  = (unsigned int*)(ws + OFF_FLAGS);
  unsigned long long* keepw  = (unsigned long long*)(ws + OFF_KEEPW);
  unsigned long long* mask   = (unsigned long long*)(ws + OFF_MASK);

  hipMemsetAsync(ws, 0, ZERO_BYTES, stream);
  hist_kernel<<<512, 256, 0, stream>>>((const float4*)score, hist);
  thresh_kernel<<<1, 64, 0, stream>>>(hist, meta);
  compact_kernel<<<512, 256, 0, stream>>>((const float4*)score, meta, keys);
  sort_kernel<<<1, 1024, 0, stream>>>(keys, sorted);
  decode_kernel<<<8, 256, 0, stream>>>(sorted, (const float4*)anchors,
                                       (const float4*)boxreg, boxes, flags);
  mask_kernel<<<M_TOP * 32, 64, 0, stream>>>(boxes, mask);
  reduce_kernel<<<1, 64, 0, stream>>>(mask, flags, keepw);
  final_kernel<<<8, 256, 0, stream>>>(boxes, keepw, out);
}

// Round 2
// 254.840 us; speedup vs baseline: 1.1417x; 1.1417x over previous
//
#include <hip/hip_runtime.h>

#define N_ANCHORS 4000000
#define NPAIR4    2000000      // float4 count in score (N*2/4)
#define M_TOP     2000
#define NBINS     1024
#define CAP       8192
#define NMS_THR_F 0.7f
#define SCORE_THR_F 0.5f

// workspace layout (bytes)
#define OFF_HIST   0            // 1024 u32  = 4096
#define OFF_META   4096         // 16 u32    = 64   (meta[0]=counter, meta[1]=T)
#define OFF_KEYS   4352         // 8192 u64  = 65536
#define OFF_SORTED 69888        // 2000 u64  = 16000
#define OFF_BOXES  85888        // 2000 f4   = 32000
#define OFF_FLAGS  117888       // 2000 u32  = 8000
#define OFF_KEEPW  125888       // 32 u64    = 256
#define OFF_MASK   131072       // 2000*32 u64 = 512000  (end 643072)
#define ZERO_BYTES 69888        // hist + meta + keys

// ---------------- pass 1: histogram of score[:,1] bits ----------------
__global__ void hist_kernel(const float4* __restrict__ s4, unsigned int* __restrict__ hist) {
  __shared__ unsigned int h[NBINS];
  for (int i = threadIdx.x; i < NBINS; i += blockDim.x) h[i] = 0;
  __syncthreads();
  int nt = gridDim.x * blockDim.x;
  for (int i = blockIdx.x * blockDim.x + threadIdx.x; i < NPAIR4; i += nt) {
    float4 v = s4[i];
    if (v.y > SCORE_THR_F) {
      unsigned b = (__float_as_uint(v.y) - 0x3F000000u) >> 13;
      atomicAdd(&h[b > 1023u ? 1023u : b], 1u);
    }
    if (v.w > SCORE_THR_F) {
      unsigned b = (__float_as_uint(v.w) - 0x3F000000u) >> 13;
      atomicAdd(&h[b > 1023u ? 1023u : b], 1u);
    }
  }
  __syncthreads();
  for (int i = threadIdx.x; i < NBINS; i += blockDim.x)
    if (h[i]) atomicAdd(&hist[i], h[i]);
}

// ---------------- find bit-threshold T so that count(bits>=T) >= M ----------------
__global__ void thresh_kernel(const unsigned int* __restrict__ hist, unsigned int* __restrict__ meta) {
  if (threadIdx.x == 0) {
    unsigned s = 0; int bstar = 0;
    for (int b = NBINS - 1; b >= 0; --b) {
      s += hist[b];
      if (s >= M_TOP) { bstar = b; break; }
    }
    meta[1] = 0x3F000000u + ((unsigned)bstar << 13);
  }
}

// ---------------- pass 2: compact candidate keys ----------------
__global__ void compact_kernel(const float4* __restrict__ s4, unsigned int* __restrict__ meta,
                               unsigned long long* __restrict__ keys) {
  unsigned T = meta[1];
  int nt = gridDim.x * blockDim.x;
  for (int i = blockIdx.x * blockDim.x + threadIdx.x; i < NPAIR4; i += nt) {
    float4 v = s4[i];
    unsigned by = __float_as_uint(v.y), bw = __float_as_uint(v.w);
    if (v.y > SCORE_THR_F && by >= T) {
      unsigned pos = atomicAdd(&meta[0], 1u);
      if (pos < CAP)
        keys[pos] = ((unsigned long long)by << 32) |
                    (unsigned long long)(0xFFFFFFFFu - (unsigned)(2 * i));
    }
    if (v.w > SCORE_THR_F && bw >= T) {
      unsigned pos = atomicAdd(&meta[0], 1u);
      if (pos < CAP)
        keys[pos] = ((unsigned long long)bw << 32) |
                    (unsigned long long)(0xFFFFFFFFu - (unsigned)(2 * i + 1));
    }
  }
}

// ---------------- single-block bitonic sort (top-2000 of <=8192) ----------------
// sort ascending on ~key  ==  descending on key (value desc, index asc on ties)
__global__ __launch_bounds__(1024) void sort_kernel(const unsigned long long* __restrict__ keys,
                                                    unsigned long long* __restrict__ sorted) {
  __shared__ unsigned long long A[CAP];   // 64 KB
  int tid = threadIdx.x;
  for (int i = tid; i < CAP; i += 1024) A[i] = ~keys[i];
  for (unsigned k = 2; k <= CAP; k <<= 1) {
    for (unsigned j = k >> 1; j; j >>= 1) {
      __syncthreads();
      for (unsigned t = tid; t < CAP / 2; t += 1024) {
        unsigned i = ((t & ~(j - 1)) << 1) | (t & (j - 1));
        unsigned p = i | j;
        bool up = ((i & k) == 0);
        unsigned long long a = A[i], b = A[p];
        if ((a > b) == up) { A[i] = b; A[p] = a; }
      }
    }
  }
  __syncthreads();
  for (int i = tid; i < M_TOP; i += 1024) sorted[i] = ~A[i];
}

// ---------------- decode + clip + keep0 flags (strict IEEE fp32, numpy op order) ----------------
__global__ void decode_kernel(const unsigned long long* __restrict__ sorted,
                              const float4* __restrict__ anchors,
                              const float4* __restrict__ deltas,
                              float4* __restrict__ boxes,
                              unsigned int* __restrict__ flags) {
  int i = blockIdx.x * blockDim.x + threadIdx.x;
  if (i >= M_TOP) return;
  unsigned long long key = sorted[i];
  float4 outb = make_float4(0.f, 0.f, 0.f, 0.f);
  unsigned keep0 = 0;
  if (key != 0ull) {   // real candidate (valid == true)
    unsigned idx = 0xFFFFFFFFu - (unsigned)(key & 0xFFFFFFFFull);
    float4 a = anchors[idx];
    float4 d = deltas[idx];
    float w  = __fsub_rn(a.z, a.x);
    float h  = __fsub_rn(a.w, a.y);
    float cx = __fadd_rn(a.x, __fmul_rn(0.5f, w));
    float cy = __fadd_rn(a.y, __fmul_rn(0.5f, h));
    float ncx = __fadd_rn(cx, __fmul_rn(d.x, w));
    float ncy = __fadd_rn(cy, __fmul_rn(d.y, h));
    float e2 = (float)exp((double)d.z);   // ~correctly-rounded fp32 exp
    float e3 = (float)exp((double)d.w);
    float nw = __fmul_rn(w, e2);
    float nh = __fmul_rn(h, e3);
    float hx = __fmul_rn(0.5f, nw);
    float hy = __fmul_rn(0.5f, nh);
    float x1 = __fsub_rn(ncx, hx), y1 = __fsub_rn(ncy, hy);
    float x2 = __fadd_rn(ncx, hx), y2 = __fadd_rn(ncy, hy);
    x1 = fminf(fmaxf(x1, 0.f), 1024.f);
    y1 = fminf(fmaxf(y1, 0.f), 1024.f);
    x2 = fminf(fmaxf(x2, 0.f), 1024.f);
    y2 = fminf(fmaxf(y2, 0.f), 1024.f);
    bool big = (__fsub_rn(x2, x1) >= 1.0f) && (__fsub_rn(y2, y1) >= 1.0f);
    keep0 = big ? 1u : 0u;
    outb = make_float4(x1, y1, x2, y2);
  }
  boxes[i] = outb;
  flags[i] = keep0;
}

// ---------------- suppression bitmask: mask[i][w] bit l = (iou(i, w*64+l) > thr) & (col > i) ----------------
__global__ __launch_bounds__(64) void mask_kernel(const float4* __restrict__ boxes,
                                                  unsigned long long* __restrict__ mask) {
  int row  = blockIdx.x >> 5;
  int word = blockIdx.x & 31;
  int lane = threadIdx.x;
  int col  = word * 64 + lane;
  float4 bi = boxes[row];
  float4 bj = boxes[col < M_TOP ? col : 0];
  float ai = __fmul_rn(__fsub_rn(bi.z, bi.x), __fsub_rn(bi.w, bi.y));
  float aj = __fmul_rn(__fsub_rn(bj.z, bj.x), __fsub_rn(bj.w, bj.y));
  float ltx = fmaxf(bi.x, bj.x), lty = fmaxf(bi.y, bj.y);
  float rbx = fminf(bi.z, bj.z), rby = fminf(bi.w, bj.w);
  float wx = fmaxf(__fsub_rn(rbx, ltx), 0.f);
  float wy = fmaxf(__fsub_rn(rby, lty), 0.f);
  float inter = __fmul_rn(wx, wy);
  float den = __fadd_rn(__fsub_rn(__fadd_rn(ai, aj), inter), 1e-9f);
  float iou = __fdiv_rn(inter, den);
  bool pred = (col > row) && (col < M_TOP) && (iou > NMS_THR_F);
  unsigned long long bal = __ballot(pred);
  if (lane == 0) mask[(size_t)row * 32 + word] = bal;
}

// ---------------- serial greedy NMS reduce (1 wave, register-preloaded chunks) ----------------
// lane l: half = l>>5, myw = l&31. Per chunk c (rows c*64 .. c*64+63):
//   diag (1 reg): lane b holds mask[row_b][c]  -> broadcast via shfl in serial loop
//   mw[32] regs : lane l holds mask[row_{half*32+b}][myw] for b=0..31
// Serial loop is then pure VALU+shfl; one coalesced load burst per chunk.
__global__ __launch_bounds__(64) void reduce_kernel(const unsigned long long* __restrict__ mask,
                                                    const unsigned int* __restrict__ flags,
                                                    unsigned long long* __restrict__ keepw) {
  int lane = threadIdx.x;
  int half = lane >> 5;
  int myw  = lane & 31;
  unsigned long long k0 = 0, rem = 0;
  // pack keep0 flags into 32 words (lane w holds word w)
  for (int w = 0; w < 32; ++w) {
    int i = w * 64 + lane;
    unsigned f = (i < M_TOP) ? flags[i] : 0u;
    unsigned long long bal = __ballot(f != 0u);
    if (lane == w) k0 = bal;
  }
  for (int c = 0; c < 32; ++c) {
    const unsigned long long* rowbase = mask + (size_t)(c * 64) * 32;
    // preload diagonal word for row 'lane' of this chunk (clamp OOB rows; their am bits are 0)
    int rd = c * 64 + lane;
    unsigned long long diag = rowbase[(size_t)(rd < M_TOP ? lane : 0) * 32 + c];
    // preload my word for the 32 rows of my half (clamped for rows >= M_TOP)
    unsigned long long mw[32];
    #pragma unroll
    for (int b = 0; b < 32; ++b) {
      int r = half * 32 + b;
      int rr = (c * 64 + r < M_TOP) ? r : 0;
      mw[b] = rowbase[(size_t)rr * 32 + myw];
    }
    unsigned long long cur = __shfl(k0 & ~rem, c);   // alive word for this chunk
    #pragma unroll
    for (int b = 0; b < 64; ++b) {
      unsigned long long am = ((cur >> b) & 1ull) ? ~0ull : 0ull;
      unsigned long long mc = __shfl(diag, b);       // row b's diagonal word
      cur &= ~(mc & am);                             // suppress later bits in this chunk
      if ((b >> 5) == half) rem |= mw[b & 31] & am;  // accumulate future-chunk suppression
    }
    rem |= __shfl(rem, lane ^ 32);                   // merge halves -> total per word
  }
  if (lane < 32) keepw[lane] = k0 & ~rem;
}

// ---------------- write outputs: boxes_out (2000x4) then keep (2000) ----------------
__global__ void final_kernel(const float4* __restrict__ boxes,
                             const unsigned long long* __restrict__ keepw,
                             float* __restrict__ out) {
  int i = blockIdx.x * blockDim.x + threadIdx.x;
  if (i >= M_TOP) return;
  unsigned long long wbits = keepw[i >> 6];
  int kb = (int)((wbits >> (i & 63)) & 1ull);
  float4 b = boxes[i];
  float4 o = kb ? b : make_float4(0.f, 0.f, 0.f, 0.f);
  ((float4*)out)[i] = o;
  out[4 * M_TOP + i] = kb ? 1.0f : 0.0f;
}

extern "C" void kernel_launch(void* const* d_in, const int* in_sizes, int n_in,
                              void* d_out, int out_size, void* d_ws, size_t ws_size,
                              hipStream_t stream) {
  const float* anchors = (const float*)d_in[0];
  const float* score   = (const float*)d_in[1];
  const float* boxreg  = (const float*)d_in[2];
  float* out = (float*)d_out;
  char* ws = (char*)d_ws;

  unsigned int*       hist   = (unsigned int*)(ws + OFF_HIST);
  unsigned int*       meta   = (unsigned int*)(ws + OFF_META);
  unsigned long long* keys   = (unsigned long long*)(ws + OFF_KEYS);
  unsigned long long* sorted = (unsigned long long*)(ws + OFF_SORTED);
  float4*             boxes  = (float4*)(ws + OFF_BOXES);
  unsigned int*       flags  = (unsigned int*)(ws + OFF_FLAGS);
  unsigned long long* keepw  = (unsigned long long*)(ws + OFF_KEEPW);
  unsigned long long* mask   = (unsigned long long*)(ws + OFF_MASK);

  hipMemsetAsync(ws, 0, ZERO_BYTES, stream);
  hist_kernel<<<1024, 256, 0, stream>>>((const float4*)score, hist);
  thresh_kernel<<<1, 64, 0, stream>>>(hist, meta);
  compact_kernel<<<1024, 256, 0, stream>>>((const float4*)score, meta, keys);
  sort_kernel<<<1, 1024, 0, stream>>>(keys, sorted);
  decode_kernel<<<8, 256, 0, stream>>>(sorted, (const float4*)anchors,
                                       (const float4*)boxreg, boxes, flags);
  mask_kernel<<<M_TOP * 32, 64, 0, stream>>>(boxes, mask);
  reduce_kernel<<<1, 64, 0, stream>>>(mask, flags, keepw);
  final_kernel<<<8, 256, 0, stream>>>(boxes, keepw, out);
}